// Round 1
// 129.587 us; speedup vs baseline: 1.0042x; 1.0042x over previous
//
#include <hip/hip_runtime.h>

#define NB 2097152
#define HM 8
#define HP 8
#define NV 2
#define PTS 4   // points per thread (was 2): amortize per-wave s_load stalls, 2x ILP

// NOTE: clang's amdgcn builtins (cvt_pkrtz, fdot2) use __fp16 vectors.
typedef __fp16 h2 __attribute__((ext_vector_type(2)));

// Packed-weight workspace layout (32-bit words; h2 pairs unless noted f32):
#define OFF_MW0   0     // mW0p[8]        pairs over i, scaled log2(e)  (ELU fold)
#define OFF_MW1   8     // mW1p[8][4]     pairs over i, UNSCALED (L2E*ln2 cancels)
#define OFF_MW2   40    // mW2p[4][4]     pairs over i, scaled ln2 (undo h-tilde)
#define OFF_PW1F  56    // pW1f[v][8]     pairs over i, scaled 2*log2(e) (tanh fold)
#define OFF_PW2F  72    // pW2f[v][8][4]  pairs over p, scaled 2*log2(e)
#define OFF_PW3F  136   // pW3f[v][4]     pairs over p, scaled -log2(e)  (sigmoid fold)
#define OFF_PW2T  144   // V2T[v][8][4]   pairs over q, = 0.5*W3[q]*W2[q][p] (W3+mean fold)
#define OFF_PW1T  208   // pW1T[v][2][4]  pairs over p (transposed, unscaled)
#define FOFF_PB1  224   // f32 2*log2(e)*pb1 [16]
#define FOFF_PB2  240   // f32 2*log2(e)*pb2 [16]
#define FOFF_PB3  256   // f32 -log2(e)*pb3 [2]
#define FOFF_MB0  260   // f32 log2(e)*mb0 [8]
#define FOFF_MB1  268   // f32 log2(e)*mb1 [8]

#define L2E  1.4426950408889634f
#define LN2  0.6931471805599453f
#define TL2E 2.8853901635333640f   // 2*log2(e)

static __device__ __forceinline__ h2 pk(float a, float b) {
    return __builtin_amdgcn_cvt_pkrtz(a, b);
}
static __device__ __forceinline__ float fdot2(h2 a, h2 b, float c) {
    return __builtin_amdgcn_fdot2(a, b, c, false);   // v_dot2_f32_f16
}
static __device__ __forceinline__ unsigned h2bits(h2 v) {
    union { h2 h; unsigned u; } c; c.h = v; return c.u;
}
static __device__ __forceinline__ h2 bits2h(unsigned u) {
    union { h2 h; unsigned u; } c; c.u = u; return c.h;
}
static __device__ __forceinline__ h2 pkfma(h2 a, h2 b, h2 c) {
    return __builtin_elementwise_fma(a, b, c);       // v_pk_fma_f16
}

// ---------------- prep: pack/scale weights into ws ----------------
__global__ void prep_kernel(
    const float* __restrict__ mW0, const float* __restrict__ mb0,
    const float* __restrict__ mW1, const float* __restrict__ mb1,
    const float* __restrict__ mW2,
    const float* __restrict__ pW1, const float* __restrict__ pb1,
    const float* __restrict__ pW2, const float* __restrict__ pb2,
    const float* __restrict__ pW3, const float* __restrict__ pb3,
    unsigned* __restrict__ ws)
{
    const int t = threadIdx.x;           // 64 threads
    float* wf = (float*)ws;

    if (t < 8)  ws[OFF_MW0 + t] = h2bits(pk(L2E*mW0[t*2], L2E*mW0[t*2+1]));
    if (t < 32) { int o = t >> 2, k = t & 3;
        ws[OFF_MW1 + t] = h2bits(pk(mW1[o*8 + 2*k], mW1[o*8 + 2*k + 1])); }
    if (t < 16) { int o = t >> 2, k = t & 3;
        ws[OFF_MW2 + t] = h2bits(pk(LN2*mW2[o*8 + 2*k], LN2*mW2[o*8 + 2*k + 1])); }
    if (t < 16) ws[OFF_PW1F + t] = h2bits(pk(TL2E*pW1[t*2], TL2E*pW1[t*2+1]));
    { int v = t >> 5, q = (t >> 2) & 7, k = t & 3;
      ws[OFF_PW2F + t] = h2bits(pk(TL2E*pW2[v*64 + q*8 + 2*k],
                                   TL2E*pW2[v*64 + q*8 + 2*k + 1])); }
    if (t < 8) { int v = t >> 2, k = t & 3;
        ws[OFF_PW3F + t] = h2bits(pk(-L2E*pW3[v*8 + 2*k], -L2E*pW3[v*8 + 2*k + 1])); }
    { // V2T: transposed W2, W3 row-factor AND the NV-mean 0.5 folded in.
      int v = t >> 5, p = (t >> 2) & 7, k = t & 3;
      ws[OFF_PW2T + t] = h2bits(pk(0.5f*pW3[v*8 + 2*k]     * pW2[v*64 + (2*k)*8 + p],
                                   0.5f*pW3[v*8 + 2*k + 1] * pW2[v*64 + (2*k+1)*8 + p])); }
    if (t < 16) { int v = t >> 3, i = (t >> 2) & 1, k = t & 3;
        ws[OFF_PW1T + t] = h2bits(pk(pW1[v*16 + (2*k)*2 + i],
                                     pW1[v*16 + (2*k+1)*2 + i])); }
    if (t < 16) wf[FOFF_PB1 + t] = TL2E * pb1[t];
    if (t < 16) wf[FOFF_PB2 + t] = TL2E * pb2[t];
    if (t < 2)  wf[FOFF_PB3 + t] = -L2E * pb3[t];
    if (t < 8)  wf[FOFF_MB0 + t] = L2E * mb0[t];
    if (t < 8)  wf[FOFF_MB1 + t] = L2E * mb1[t];
}

// Scaled ELU on pre-scaled z' (= L2E*z): returns L2E*elu(z) =
// med3(z', L2E*2^{z'} - L2E, 0). 3 ops: exp2, fma, med3. NaN-free.
static __device__ __forceinline__ float elus(float zp) {
    float e = __builtin_amdgcn_exp2f(zp);
    return __builtin_amdgcn_fmed3f(zp, fmaf(e, L2E, -L2E), 0.f);
}
// sigmoid-core from pre-scaled z (= -L2E*z or 2*L2E*z): r = 1/(2^z + 1)
static __device__ __forceinline__ float sigr(float zp) {
    float e = __builtin_amdgcn_exp2f(zp);
    return __builtin_amdgcn_rcpf(e + 1.f);
}
// ss = s(1-s), s = outer sigmoid of u in (0,1): s-0.5 = u*c(u) cubic fit.
static __device__ __forceinline__ float ss01(float u) {
    float c = fmaf(u, fmaf(u, -0.01566459f, -0.0040905f), 0.2508141f);
    float m = u * c;
    return fmaf(-m, m, 0.25f);
}

// Layer-lockstep: PTS points advance together; each weight s_loaded once per wave.
__global__ __launch_bounds__(256, 2) void odefunc_kernel(
    const float* __restrict__ x,
    const unsigned* __restrict__ W,
    const float* __restrict__ mb2,
    float* __restrict__ out)
{
    const int tid = blockIdx.x * blockDim.x + threadIdx.x;
    const int b0  = tid * PTS;               // PTS points per thread, lockstep
    const float* Wf = (const float*)W;
    const h2 oneh = { (__fp16)1.f, (__fp16)1.f };
    const h2 m2h  = { (__fp16)-2.f, (__fp16)-2.f };

    const float4 xa = *reinterpret_cast<const float4*>(x + b0 * 2);
    const float4 xb = *reinterpret_cast<const float4*>(x + b0 * 2 + 4);
    h2 xh[PTS] = { pk(xa.x, xa.y), pk(xa.z, xa.w),
                   pk(xb.x, xb.y), pk(xb.z, xb.w) };

    // ---- m-branch: 2 -> 8 -> 8 -> 4, scaled-ELU chain (ELU fused into dot loop) ----
    float h0[PTS][8];
    h2 hp[PTS][4];
#pragma unroll
    for (int o = 0; o < 8; ++o) {
        h2 w = bits2h(W[OFF_MW0 + o]);
        float b = Wf[FOFF_MB0 + o];
#pragma unroll
        for (int pt = 0; pt < PTS; ++pt) h0[pt][o] = elus(fdot2(xh[pt], w, b));
    }
#pragma unroll
    for (int k = 0; k < 4; ++k)
#pragma unroll
        for (int pt = 0; pt < PTS; ++pt) hp[pt][k] = pk(h0[pt][2*k], h0[pt][2*k+1]);

    float h1[PTS][8];
#pragma unroll
    for (int o = 0; o < 8; ++o) {
        float b = Wf[FOFF_MB1 + o];
        float a[PTS];
#pragma unroll
        for (int pt = 0; pt < PTS; ++pt) a[pt] = b;
#pragma unroll
        for (int k = 0; k < 4; ++k) {
            h2 w = bits2h(W[OFF_MW1 + o*4 + k]);
#pragma unroll
            for (int pt = 0; pt < PTS; ++pt) a[pt] = fdot2(hp[pt][k], w, a[pt]);
        }
#pragma unroll
        for (int pt = 0; pt < PTS; ++pt) h1[pt][o] = elus(a[pt]);
    }
#pragma unroll
    for (int k = 0; k < 4; ++k)
#pragma unroll
        for (int pt = 0; pt < PTS; ++pt) hp[pt][k] = pk(h1[pt][2*k], h1[pt][2*k+1]);

    float m2[PTS], mag0[PTS], mag3[PTS];
    {
        float bm[PTS][4];
#pragma unroll
        for (int o = 0; o < 4; ++o) {
            float bb = mb2[o];
            float a[PTS];
#pragma unroll
            for (int pt = 0; pt < PTS; ++pt) a[pt] = bb;
#pragma unroll
            for (int k = 0; k < 4; ++k) {
                h2 w = bits2h(W[OFF_MW2 + o*4 + k]);
#pragma unroll
                for (int pt = 0; pt < PTS; ++pt) a[pt] = fdot2(hp[pt][k], w, a[pt]);
            }
#pragma unroll
            for (int pt = 0; pt < PTS; ++pt) bm[pt][o] = a[pt];
        }
#pragma unroll
        for (int pt = 0; pt < PTS; ++pt) {
            m2[pt]   = bm[pt][0]*bm[pt][1] + bm[pt][2]*bm[pt][3];
            mag0[pt] = bm[pt][0]*bm[pt][0] + bm[pt][2]*bm[pt][2];
            mag3[pt] = bm[pt][1]*bm[pt][1] + bm[pt][3]*bm[pt][3];
        }
    }

    // ---- p-branch: NV nets, fwd + analytic input-grad bwd ----
    float g0[PTS] = {0.f,0.f,0.f,0.f}, g1[PTS] = {0.f,0.f,0.f,0.f};
#pragma unroll
    for (int v = 0; v < NV; ++v) {
        float r[PTS][8];
        h2 f1p[PTS][4], f2p[PTS][4];

        // f1: sigmoid-core fused per output (interleaves trans with dot2s)
#pragma unroll
        for (int o = 0; o < 8; ++o) {
            h2 w = bits2h(W[OFF_PW1F + v*8 + o]);
            float b = Wf[FOFF_PB1 + v*8 + o];
#pragma unroll
            for (int pt = 0; pt < PTS; ++pt) r[pt][o] = sigr(fdot2(xh[pt], w, b));
        }
#pragma unroll
        for (int k = 0; k < 4; ++k)
#pragma unroll
            for (int pt = 0; pt < PTS; ++pt)
                f1p[pt][k] = pkfma(pk(r[pt][2*k], r[pt][2*k+1]), m2h, oneh);   // tanh = 1-2r

        // f2
#pragma unroll
        for (int q = 0; q < 8; ++q) {
            float b = Wf[FOFF_PB2 + v*8 + q];
            float a[PTS];
#pragma unroll
            for (int pt = 0; pt < PTS; ++pt) a[pt] = b;
#pragma unroll
            for (int k = 0; k < 4; ++k) {
                h2 w = bits2h(W[OFF_PW2F + v*32 + q*4 + k]);
#pragma unroll
                for (int pt = 0; pt < PTS; ++pt) a[pt] = fdot2(f1p[pt][k], w, a[pt]);
            }
#pragma unroll
            for (int pt = 0; pt < PTS; ++pt) r[pt][q] = sigr(a[pt]);
        }
#pragma unroll
        for (int k = 0; k < 4; ++k)
#pragma unroll
            for (int pt = 0; pt < PTS; ++pt)
                f2p[pt][k] = pkfma(pk(r[pt][2*k], r[pt][2*k+1]), m2h, oneh);

        // z3 -> inner sigmoid -> outer s(1-s)
        float ss[PTS];
        {
            float z3b = Wf[FOFF_PB3 + v];            // pre-scaled by -log2(e)
            float z3[PTS];
#pragma unroll
            for (int pt = 0; pt < PTS; ++pt) z3[pt] = z3b;
#pragma unroll
            for (int k = 0; k < 4; ++k) {
                h2 w = bits2h(W[OFF_PW3F + v*4 + k]);
#pragma unroll
                for (int pt = 0; pt < PTS; ++pt) z3[pt] = fdot2(f2p[pt][k], w, z3[pt]);
            }
#pragma unroll
            for (int pt = 0; pt < PTS; ++pt) ss[pt] = ss01(sigr(z3[pt]));
        }

        // t2 = 1 - f2^2, packed
        h2 t2p[PTS][4];
#pragma unroll
        for (int k = 0; k < 4; ++k)
#pragma unroll
            for (int pt = 0; pt < PTS; ++pt)
                t2p[pt][k] = pkfma(-f2p[pt][k], f2p[pt][k], oneh);

        // a[p] = sum_q 0.5*W3[q](1-f2q^2) W2[q][p] — fused into gpp pairs (low live state)
        h2 gpp[PTS][4];
#pragma unroll
        for (int k = 0; k < 4; ++k) {
            float a0[PTS] = {0.f,0.f,0.f,0.f}, a1[PTS] = {0.f,0.f,0.f,0.f};
#pragma unroll
            for (int j = 0; j < 4; ++j) {
                h2 w0 = bits2h(W[OFF_PW2T + v*32 + (2*k)*4 + j]);
                h2 w1 = bits2h(W[OFF_PW2T + v*32 + (2*k+1)*4 + j]);
#pragma unroll
                for (int pt = 0; pt < PTS; ++pt) {
                    a0[pt] = fdot2(t2p[pt][j], w0, a0[pt]);
                    a1[pt] = fdot2(t2p[pt][j], w1, a1[pt]);
                }
            }
#pragma unroll
            for (int pt = 0; pt < PTS; ++pt) {
                h2 t1 = pkfma(-f1p[pt][k], f1p[pt][k], oneh);
                gpp[pt][k] = pk(a0[pt], a1[pt]) * t1;
            }
        }

        float gi0[PTS] = {0.f,0.f,0.f,0.f}, gi1[PTS] = {0.f,0.f,0.f,0.f};
#pragma unroll
        for (int k = 0; k < 4; ++k) {
            h2 w0 = bits2h(W[OFF_PW1T + v*8 + k]);
            h2 w1 = bits2h(W[OFF_PW1T + v*8 + 4 + k]);
#pragma unroll
            for (int pt = 0; pt < PTS; ++pt) {
                gi0[pt] = fdot2(gpp[pt][k], w0, gi0[pt]);
                gi1[pt] = fdot2(gpp[pt][k], w1, gi1[pt]);
            }
        }
#pragma unroll
        for (int pt = 0; pt < PTS; ++pt) {
            g0[pt] = fmaf(ss[pt], gi0[pt], g0[pt]);
            g1[pt] = fmaf(ss[pt], gi1[pt], g1[pt]);
        }
    }

    float rr[PTS][2];
#pragma unroll
    for (int pt = 0; pt < PTS; ++pt) {       // 0.5 mean already folded into V2T
        rr[pt][0] = mag0[pt]*g0[pt] + m2[pt]*g1[pt];
        rr[pt][1] = m2[pt]*g0[pt] + mag3[pt]*g1[pt];
    }
    *reinterpret_cast<float4*>(out + b0 * 2)     = make_float4(rr[0][0], rr[0][1], rr[1][0], rr[1][1]);
    *reinterpret_cast<float4*>(out + b0 * 2 + 4) = make_float4(rr[2][0], rr[2][1], rr[3][0], rr[3][1]);
}

extern "C" void kernel_launch(void* const* d_in, const int* in_sizes, int n_in,
                              void* d_out, int out_size, void* d_ws, size_t ws_size,
                              hipStream_t stream) {
    // order: t, x, mW0, mb0, mW1, mb1, mW2, mb2, pW1, pb1, pW2, pb2, pW3, pb3
    const float* x   = (const float*)d_in[1];
    const float* mW0 = (const float*)d_in[2];
    const float* mb0 = (const float*)d_in[3];
    const float* mW1 = (const float*)d_in[4];
    const float* mb1 = (const float*)d_in[5];
    const float* mW2 = (const float*)d_in[6];
    const float* mb2 = (const float*)d_in[7];
    const float* pW1 = (const float*)d_in[8];
    const float* pb1 = (const float*)d_in[9];
    const float* pW2 = (const float*)d_in[10];
    const float* pb2 = (const float*)d_in[11];
    const float* pW3 = (const float*)d_in[12];
    const float* pb3 = (const float*)d_in[13];
    unsigned* ws = (unsigned*)d_ws;
    float* out = (float*)d_out;

    prep_kernel<<<1, 64, 0, stream>>>(mW0, mb0, mW1, mb1, mW2,
                                      pW1, pb1, pW2, pb2, pW3, pb3, ws);

    const int threads = 256;
    const int blocks  = NB / (threads * PTS);   // 2048 blocks
    odefunc_kernel<<<blocks, threads, 0, stream>>>(x, ws, mb2, out);
}